// Round 14
// baseline (37.389 us; speedup 1.0000x reference)
//
#include <hip/hip_runtime.h>

typedef float f4 __attribute__((ext_vector_type(4)));
typedef _Float16 h2 __attribute__((ext_vector_type(2)));

#define Hdim 64
#define Wdim 64
#define Cdim 256
#define HW (Hdim * Wdim)

// v_dot2_f32_f16: d = a.x*b.x + a.y*b.y + c  (fp32 accumulate)
__device__ __forceinline__ float fdot2f(h2 a, h2 b, float c) {
#if __has_builtin(__builtin_amdgcn_fdot2)
    return __builtin_amdgcn_fdot2(a, b, c, false);
#else
    float d;
    asm("v_dot2_f32_f16 %0, %1, %2, %3" : "=v"(d) : "v"(a), "v"(b), "v"(c));
    return d;
#endif
}

// ---------------------------------------------------------------------------
// Pack kernel: x fp32 [b][c][h][w] -> ws half2 [b][c/2][h][w] = {x[2cp],x[2cp+1]}
// ---------------------------------------------------------------------------
__global__ __launch_bounds__(512) void pack_kernel(const float* __restrict__ x,
                                                   float* __restrict__ pw)
{
    const int tid = blockIdx.x * 512 + threadIdx.x;   // 0..524287
    const int wq = tid & 15;
    const int h  = (tid >> 4) & 63;
    const int cp = (tid >> 10) & 127;
    const int b  = tid >> 17;
    const float* s0 = x + ((size_t)b * Cdim + 2 * cp) * HW + h * 64 + wq * 4;
    f4 v0 = *(const f4*)s0;
    f4 v1 = *(const f4*)(s0 + HW);
    f4 ov;
    #pragma unroll
    for (int p = 0; p < 4; ++p) {
        h2 o;
        o[0] = (_Float16)v0[p];
        o[1] = (_Float16)v1[p];
        ov[p] = __builtin_bit_cast(float, o);
    }
    *(f4*)(pw + ((size_t)b * 128 + cp) * HW + h * 64 + wq * 4) = ov;
}

// ---------------------------------------------------------------------------
// Main kernel: f16 (r13) + w-quarter split for occupancy.
// 1024 blocks x 512 thr; XCD decode bid&7 -> (batch, 32-row band) (2.4MB < L2).
// Natural launch_bounds(512): r6-r9 ledger says forced min-waves caps spill;
// f16 per-thread state ~60 VGPR -> if <=64, HW gives 8 waves/SIMD = 4 blk/CU.
// #pragma unroll 2 on phase-A loop (unroll-1 demotes to LDS: r8; full unroll
// hoists loads past 64 VGPR: r7).
// Phase A: 8 iters x 16 channel-pair partitions; 28 dot2/iter, fp32 acc.
// Phase B: 1 pair/thread x 7 dy; v_pk_fma_f16, f16 acc.
// ---------------------------------------------------------------------------
__global__ __launch_bounds__(512) void selfattn_f16(const float* __restrict__ pwf,
                                                    float* __restrict__ out)
{
    const int bid = blockIdx.x;
    const int k   = bid & 7;
    const int seq = bid >> 3;            // 0..127
    const int b   = k >> 1;
    const int h   = (k & 1) * 32 + (seq >> 2);
    const int wbase = (seq & 3) * 16;    // w-quarter
    const int t = threadIdx.x;           // 0..511

    __shared__ float simRed[49][16];
    __shared__ __align__(16) h2 attnH[49][16];   // (a,a) packed
    __shared__ float redBuf[7][16];
    __shared__ float psumBuf[7][16];

    const float* pw = pwf + (size_t)b * (128 * HW);   // h2 elements viewed as float

    // ---------------- Phase A: sim[k][w] over 128 channel-pairs ----------------
    // thread = (w4: bits 0..1, cp: bits 2..5, dy: wave). iter i: pair = i*16+cp.
    {
        const int w4 = t & 3;
        const int cp = (t >> 2) & 15;
        const int dy = t >> 6;           // wave-uniform; dy==7 idle
        const int lw0 = w4 * 4;
        const int w0g = wbase + lw0;

        if (dy < 7) {
            float sim[7][4];
            #pragma unroll
            for (int dx = 0; dx < 7; ++dx)
                #pragma unroll
                for (int p = 0; p < 4; ++p) sim[dx][p] = 0.f;

            const int row = h + dy - 3;
            if (row >= 0 && row < Hdim) {
                const bool hasL = (w0g != 0);
                const bool hasR = (w0g != 60);
                const float* xr = pw + (size_t)cp * HW + row * 64;
                const float* xc = pw + (size_t)cp * HW + h   * 64;
                #pragma unroll 2
                for (int i = 0; i < 8; ++i) {
                    float fw[12];
                    if (hasL) {
                        f4 v = *(const f4*)(xr + w0g - 4);
                        fw[0]=v.x; fw[1]=v.y; fw[2]=v.z; fw[3]=v.w;
                    } else { fw[0]=0.f; fw[1]=0.f; fw[2]=0.f; fw[3]=0.f; }
                    {
                        f4 v = *(const f4*)(xr + w0g);
                        fw[4]=v.x; fw[5]=v.y; fw[6]=v.z; fw[7]=v.w;
                    }
                    if (hasR) {
                        f4 v = *(const f4*)(xr + w0g + 4);
                        fw[8]=v.x; fw[9]=v.y; fw[10]=v.z; fw[11]=v.w;
                    } else { fw[8]=0.f; fw[9]=0.f; fw[10]=0.f; fw[11]=0.f; }
                    f4 cen = *(const f4*)(xc + w0g);
                    h2 f2[12], cen2[4];
                    #pragma unroll
                    for (int j = 0; j < 12; ++j) f2[j] = __builtin_bit_cast(h2, fw[j]);
                    #pragma unroll
                    for (int p = 0; p < 4; ++p) cen2[p] = __builtin_bit_cast(h2, cen[p]);
                    #pragma unroll
                    for (int dx = 0; dx < 7; ++dx)
                        #pragma unroll
                        for (int p = 0; p < 4; ++p)
                            sim[dx][p] = fdot2f(cen2[p], f2[dx + p + 1], sim[dx][p]);
                    xr += 16 * HW;
                    xc += 16 * HW;
                }
            }
            // reduce over 16 channel partitions (lane bits 2..5)
            #pragma unroll
            for (int dx = 0; dx < 7; ++dx)
                #pragma unroll
                for (int p = 0; p < 4; ++p) {
                    float v = sim[dx][p];
                    v += __shfl_xor(v, 4);
                    v += __shfl_xor(v, 8);
                    v += __shfl_xor(v, 16);
                    v += __shfl_xor(v, 32);
                    sim[dx][p] = v;
                }
            if (cp == 0) {
                #pragma unroll
                for (int dx = 0; dx < 7; ++dx)
                    *(f4*)&simRed[dy * 7 + dx][lw0] = *(const f4*)sim[dx];
            }
        }
    }
    __syncthreads();

    // ---------------- Softmax over k=49; attn stored as (a,a) half2 ----------------
    {
        const int w  = t & 15;
        const int kc = t >> 4;    // 0..31; kc<7 active
        float sred[7], e[7];
        if (kc < 7) {
            float lmax = -3.0e38f;
            #pragma unroll
            for (int jj = 0; jj < 7; ++jj) {
                float s = simRed[kc * 7 + jj][w];
                sred[jj] = s;
                lmax = fmaxf(lmax, s);
            }
            redBuf[kc][w] = lmax;
        }
        __syncthreads();
        if (kc < 7) {
            float m = redBuf[0][w];
            #pragma unroll
            for (int q = 1; q < 7; ++q) m = fmaxf(m, redBuf[q][w]);
            float ps = 0.f;
            #pragma unroll
            for (int jj = 0; jj < 7; ++jj) {
                e[jj] = __expf(sred[jj] - m);
                ps += e[jj];
            }
            psumBuf[kc][w] = ps;
        }
        __syncthreads();
        if (kc < 7) {
            float l = psumBuf[0][w];
            #pragma unroll
            for (int q = 1; q < 7; ++q) l += psumBuf[q][w];
            float rinv = 1.0f / l;
            #pragma unroll
            for (int jj = 0; jj < 7; ++jj) {
                _Float16 ah = (_Float16)(e[jj] * rinv);
                h2 av; av[0] = ah; av[1] = ah;
                attnH[kc * 7 + jj][w] = av;
            }
        }
    }
    __syncthreads();

    // ---------------- Phase B: out via v_pk_fma_f16, 1 pair/thread ----------------
    {
        const int w4 = t & 3;
        const int ci = t >> 2;           // 0..127 -> pair ci = channels 2ci,2ci+1
        const int lw0 = w4 * 4;
        const int w0g = wbase + lw0;
        const bool hasL = (w0g != 0);
        const bool hasR = (w0g != 60);

        h2 acc2[4];
        #pragma unroll
        for (int p = 0; p < 4; ++p) { acc2[p][0] = (_Float16)0; acc2[p][1] = (_Float16)0; }

        for (int dy = 0; dy < 7; ++dy) {
            const int row = h + dy - 3;
            if (row < 0 || row >= Hdim) continue;   // block-uniform
            h2 a2[7][4];
            #pragma unroll
            for (int dx = 0; dx < 7; ++dx) {
                f4 v = *(const f4*)&attnH[dy * 7 + dx][lw0];
                #pragma unroll
                for (int p = 0; p < 4; ++p) a2[dx][p] = __builtin_bit_cast(h2, v[p]);
            }
            const float* xr = pw + (size_t)ci * HW + row * 64;
            float fw[12];
            if (hasL) {
                f4 v = *(const f4*)(xr + w0g - 4);
                fw[0]=v.x; fw[1]=v.y; fw[2]=v.z; fw[3]=v.w;
            } else { fw[0]=0.f; fw[1]=0.f; fw[2]=0.f; fw[3]=0.f; }
            {
                f4 v = *(const f4*)(xr + w0g);
                fw[4]=v.x; fw[5]=v.y; fw[6]=v.z; fw[7]=v.w;
            }
            if (hasR) {
                f4 v = *(const f4*)(xr + w0g + 4);
                fw[8]=v.x; fw[9]=v.y; fw[10]=v.z; fw[11]=v.w;
            } else { fw[8]=0.f; fw[9]=0.f; fw[10]=0.f; fw[11]=0.f; }
            h2 f2[12];
            #pragma unroll
            for (int j = 0; j < 12; ++j) f2[j] = __builtin_bit_cast(h2, fw[j]);
            #pragma unroll
            for (int dx = 0; dx < 7; ++dx)
                #pragma unroll
                for (int p = 0; p < 4; ++p)
                    acc2[p] += a2[dx][p] * f2[dx + p + 1];   // v_pk_fma_f16
        }

        float* ob = out + (size_t)b * (Cdim * HW) + h * Wdim + w0g;
        f4 o0, o1;
        #pragma unroll
        for (int p = 0; p < 4; ++p) {
            o0[p] = (float)acc2[p][0];
            o1[p] = (float)acc2[p][1];
        }
        *(f4*)(ob + (size_t)(2 * ci) * HW)     = o0;
        *(f4*)(ob + (size_t)(2 * ci + 1) * HW) = o1;
    }
}

// ---------------------------------------------------------------------------
// Fallback: r11 fp32 champion (40.0us) if ws is too small for the packed copy.
// ---------------------------------------------------------------------------
__global__ __launch_bounds__(512, 2) void selfattn_fb(const float* __restrict__ x,
                                                      float* __restrict__ out)
{
    const int bid = blockIdx.x;
    const int k   = bid & 7;
    const int seq = bid >> 3;
    const int b   = k >> 1;
    const int h   = (k & 1) * 32 + (seq >> 1);
    const int wbase = (seq & 1) * 32;
    const int t = threadIdx.x;

    __shared__ float simRed[49][32];
    __shared__ float attnBuf[49][32];
    __shared__ float redBuf[7][32];
    __shared__ float psumBuf[7][32];

    const float* xb = x + (size_t)b * (Cdim * HW);

    {
        const int w4 = t & 7;
        const int cp = (t >> 3) & 7;
        const int dy = t >> 6;
        const int lw0 = w4 * 4;
        const int w0g = wbase + lw0;

        if (dy < 7) {
            float sim[7][4];
            #pragma unroll
            for (int dx = 0; dx < 7; ++dx)
                #pragma unroll
                for (int p = 0; p < 4; ++p) sim[dx][p] = 0.f;

            const int row = h + dy - 3;
            if (row >= 0 && row < Hdim) {
                const bool hasL = (w0g != 0);
                const bool hasR = (w0g != 60);
                const float* xrA = xb + (size_t)cp * HW + row * Wdim;
                const float* xcA = xb + (size_t)cp * HW + h   * Wdim;
                const float* xrB = xrA + (size_t)128 * HW;
                const float* xcB = xcA + (size_t)128 * HW;
                #pragma unroll 2
                for (int i = 0; i < 16; ++i) {
                    float fA[12], fB[12];
                    if (hasL) {
                        f4 v = *(const f4*)(xrA + w0g - 4);
                        fA[0]=v.x; fA[1]=v.y; fA[2]=v.z; fA[3]=v.w;
                    } else { fA[0]=0.f; fA[1]=0.f; fA[2]=0.f; fA[3]=0.f; }
                    {
                        f4 v = *(const f4*)(xrA + w0g);
                        fA[4]=v.x; fA[5]=v.y; fA[6]=v.z; fA[7]=v.w;
                    }
                    if (hasR) {
                        f4 v = *(const f4*)(xrA + w0g + 4);
                        fA[8]=v.x; fA[9]=v.y; fA[10]=v.z; fA[11]=v.w;
                    } else { fA[8]=0.f; fA[9]=0.f; fA[10]=0.f; fA[11]=0.f; }
                    if (hasL) {
                        f4 v = *(const f4*)(xrB + w0g - 4);
                        fB[0]=v.x; fB[1]=v.y; fB[2]=v.z; fB[3]=v.w;
                    } else { fB[0]=0.f; fB[1]=0.f; fB[2]=0.f; fB[3]=0.f; }
                    {
                        f4 v = *(const f4*)(xrB + w0g);
                        fB[4]=v.x; fB[5]=v.y; fB[6]=v.z; fB[7]=v.w;
                    }
                    if (hasR) {
                        f4 v = *(const f4*)(xrB + w0g + 4);
                        fB[8]=v.x; fB[9]=v.y; fB[10]=v.z; fB[11]=v.w;
                    } else { fB[8]=0.f; fB[9]=0.f; fB[10]=0.f; fB[11]=0.f; }
                    f4 cenA = *(const f4*)(xcA + w0g);
                    f4 cenB = *(const f4*)(xcB + w0g);
                    #pragma unroll
                    for (int dx = 0; dx < 7; ++dx)
                        #pragma unroll
                        for (int p = 0; p < 4; ++p)
                            sim[dx][p] += cenA[p] * fA[dx + p + 1]
                                        + cenB[p] * fB[dx + p + 1];
                    xrA += 8 * HW;  xcA += 8 * HW;
                    xrB += 8 * HW;  xcB += 8 * HW;
                }
            }
            #pragma unroll
            for (int dx = 0; dx < 7; ++dx)
                #pragma unroll
                for (int p = 0; p < 4; ++p) {
                    float v = sim[dx][p];
                    v += __shfl_xor(v, 8);
                    v += __shfl_xor(v, 16);
                    v += __shfl_xor(v, 32);
                    sim[dx][p] = v;
                }
            if (cp == 0) {
                #pragma unroll
                for (int dx = 0; dx < 7; ++dx)
                    *(f4*)&simRed[dy * 7 + dx][lw0] = *(const f4*)sim[dx];
            }
        }
    }
    __syncthreads();

    {
        const int w  = t & 31;
        const int kc = t >> 5;
        float sred[7], e[7];
        if (kc < 7) {
            float lmax = -3.0e38f;
            #pragma unroll
            for (int jj = 0; jj < 7; ++jj) {
                float s = simRed[kc * 7 + jj][w];
                sred[jj] = s;
                lmax = fmaxf(lmax, s);
            }
            redBuf[kc][w] = lmax;
        }
        __syncthreads();
        if (kc < 7) {
            float m = redBuf[0][w];
            #pragma unroll
            for (int q = 1; q < 7; ++q) m = fmaxf(m, redBuf[q][w]);
            float ps = 0.f;
            #pragma unroll
            for (int jj = 0; jj < 7; ++jj) {
                e[jj] = __expf(sred[jj] - m);
                ps += e[jj];
            }
            psumBuf[kc][w] = ps;
        }
        __syncthreads();
        if (kc < 7) {
            float l = psumBuf[0][w];
            #pragma unroll
            for (int q = 1; q < 7; ++q) l += psumBuf[q][w];
            float rinv = 1.0f / l;
            #pragma unroll
            for (int jj = 0; jj < 7; ++jj)
                attnBuf[kc * 7 + jj][w] = e[jj] * rinv;
        }
    }
    __syncthreads();

    {
        const int w4 = t & 7;
        const int ci = t >> 3;
        const int lw0 = w4 * 4;
        const int w0g = wbase + lw0;
        const int c0 = ci * 4;
        const bool hasL = (w0g != 0);
        const bool hasR = (w0g != 60);

        float acc[4][4];
        #pragma unroll
        for (int ch = 0; ch < 4; ++ch)
            #pragma unroll
            for (int p = 0; p < 4; ++p) acc[ch][p] = 0.f;

        for (int dy = 0; dy < 7; ++dy) {
            const int row = h + dy - 3;
            if (row < 0 || row >= Hdim) continue;
            float a[7][4];
            #pragma unroll
            for (int dx = 0; dx < 7; ++dx) {
                f4 v = *(const f4*)&attnBuf[dy * 7 + dx][lw0];
                a[dx][0]=v.x; a[dx][1]=v.y; a[dx][2]=v.z; a[dx][3]=v.w;
            }
            const float* xr = xb + (size_t)c0 * HW + row * Wdim;
            #pragma unroll
            for (int ch = 0; ch < 4; ++ch) {
                float fw[12];
                if (hasL) {
                    f4 v = *(const f4*)(xr + w0g - 4);
                    fw[0]=v.x; fw[1]=v.y; fw[2]=v.z; fw[3]=v.w;
                } else { fw[0]=0.f; fw[1]=0.f; fw[2]=0.f; fw[3]=0.f; }
                {
                    f4 v = *(const f4*)(xr + w0g);
                    fw[4]=v.x; fw[5]=v.y; fw[6]=v.z; fw[7]=v.w;
                }
                if (hasR) {
                    f4 v = *(const f4*)(xr + w0g + 4);
                    fw[8]=v.x; fw[9]=v.y; fw[10]=v.z; fw[11]=v.w;
                } else { fw[8]=0.f; fw[9]=0.f; fw[10]=0.f; fw[11]=0.f; }
                #pragma unroll
                for (int dx = 0; dx < 7; ++dx)
                    #pragma unroll
                    for (int p = 0; p < 4; ++p)
                        acc[ch][p] += a[dx][p] * fw[dx + p + 1];
                xr += HW;
            }
        }

        float* ob = out + (size_t)b * (Cdim * HW) + h * Wdim + wbase;
        #pragma unroll
        for (int ch = 0; ch < 4; ++ch)
            *(f4*)(ob + (size_t)(c0 + ch) * HW + lw0) = *(const f4*)acc[ch];
    }
}

extern "C" void kernel_launch(void* const* d_in, const int* in_sizes, int n_in,
                              void* d_out, int out_size, void* d_ws, size_t ws_size,
                              hipStream_t stream)
{
    const float* x = (const float*)d_in[0];
    float* out = (float*)d_out;
    const size_t need = (size_t)4 * 128 * HW * 4;   // 8 MB packed half2
    if (ws_size >= need) {
        float* pw = (float*)d_ws;
        pack_kernel<<<dim3(1024), 512, 0, stream>>>(x, pw);
        selfattn_f16<<<dim3(1024), 512, 0, stream>>>(pw, out);
    } else {
        selfattn_fb<<<dim3(512), 512, 0, stream>>>(x, out);
    }
}

// Round 15
// 34.577 us; speedup vs baseline: 1.0813x; 1.0813x over previous
//
#include <hip/hip_runtime.h>

typedef float f4 __attribute__((ext_vector_type(4)));
typedef _Float16 h2 __attribute__((ext_vector_type(2)));

#define Hdim 64
#define Wdim 64
#define Cdim 256
#define HW (Hdim * Wdim)

// v_dot2_f32_f16: d = a.x*b.x + a.y*b.y + c  (fp32 accumulate)
__device__ __forceinline__ float fdot2f(h2 a, h2 b, float c) {
#if __has_builtin(__builtin_amdgcn_fdot2)
    return __builtin_amdgcn_fdot2(a, b, c, false);
#else
    float d;
    asm("v_dot2_f32_f16 %0, %1, %2, %3" : "=v"(d) : "v"(a), "v"(b), "v"(c));
    return d;
#endif
}

// ---------------------------------------------------------------------------
// Pack kernel: x fp32 [b][c][h][w] -> ws half2 [b][c/2][h][w] = {x[2cp],x[2cp+1]}
// ---------------------------------------------------------------------------
__global__ __launch_bounds__(512) void pack_kernel(const float* __restrict__ x,
                                                   float* __restrict__ pw)
{
    const int tid = blockIdx.x * 512 + threadIdx.x;   // 0..524287
    const int wq = tid & 15;
    const int h  = (tid >> 4) & 63;
    const int cp = (tid >> 10) & 127;
    const int b  = tid >> 17;
    const float* s0 = x + ((size_t)b * Cdim + 2 * cp) * HW + h * 64 + wq * 4;
    f4 v0 = *(const f4*)s0;
    f4 v1 = *(const f4*)(s0 + HW);
    f4 ov;
    #pragma unroll
    for (int p = 0; p < 4; ++p) {
        h2 o;
        o[0] = (_Float16)v0[p];
        o[1] = (_Float16)v1[p];
        ov[p] = __builtin_bit_cast(float, o);
    }
    *(f4*)(pw + ((size_t)b * 128 + cp) * HW + h * 64 + wq * 4) = ov;
}

// ---------------------------------------------------------------------------
// Main kernel: h-pair blocks with row-window sharing (f16).
// 256 blocks x 1024 thr (16 waves/CU, same as r13 champion) but each staged
// row-window serves BOTH rows h0,h1 (dy for h0 = dy+1's row for h1):
// phase A 5 loads -> 56 dot2 (vs 4 -> 28); phase B 24 loads -> 392 pk_fma
// (vs 42). ~1.5x fewer global loads at equal occupancy.
// XCD decode: bid&7 owns (batch, 32-row band) -> 2.4MB < 4MB per-XCD L2.
// launch_bounds(1024) forces VGPR<=128 (demand ~106); unroll 2 prevents
// full-unroll load hoisting past the cap (r7 spill mechanism).
// ---------------------------------------------------------------------------
__global__ __launch_bounds__(1024) void selfattn_hpair(const float* __restrict__ pwf,
                                                       float* __restrict__ out)
{
    const int bid = blockIdx.x;          // 0..255
    const int k   = bid & 7;
    const int seq = bid >> 3;            // 0..31
    const int b   = k >> 1;
    const int hh  = k & 1;
    const int hp  = seq >> 1;            // 0..15 h-pair in band
    const int h0  = hh * 32 + hp * 2;
    const int h1  = h0 + 1;
    const int wbase = (seq & 1) * 32;    // w-half
    const int t = threadIdx.x;           // 0..1023

    __shared__ float simPart[2][2][49][32];           // [h][g][k][w] 25,088B
    __shared__ __align__(16) h2 attnH[2][49][32];     // (a,a) packed 12,544B
    __shared__ float redBuf[2][7][32];
    __shared__ float psumBuf[2][7][32];

    const float* pw = pwf + (size_t)b * (128 * HW);   // h2 viewed as float

    // ================= Phase A =================
    // wave = (r: row slot 0..7 -> global row h0-3+r, g: channel group 0..1)
    // lane = (w4: bits 0..2, cp: bits 3..5). iter i: pair = g*8+cp+16i.
    {
        const int wave = t >> 6;
        const int r    = wave & 7;
        const int g    = wave >> 3;
        const int w4 = t & 7;
        const int cp = (t >> 3) & 7;
        const int lw0 = w4 * 4;
        const int w0g = wbase + lw0;
        const int gr = h0 - 3 + r;
        const bool grok = (gr >= 0 && gr < Hdim);
        const bool use0 = (r <= 6);      // contributes dy = r to h0
        const bool use1 = (r >= 1);      // contributes dy = r-1 to h1

        float sim0[7][4], sim1[7][4];
        #pragma unroll
        for (int dx = 0; dx < 7; ++dx)
            #pragma unroll
            for (int p = 0; p < 4; ++p) { sim0[dx][p] = 0.f; sim1[dx][p] = 0.f; }

        if (grok) {
            const bool hasL = (w0g != 0);
            const bool hasR = (w0g != 60);
            const float* xr  = pw + (size_t)(g * 8 + cp) * HW + gr * 64;
            const float* xc0 = pw + (size_t)(g * 8 + cp) * HW + h0 * 64;
            const float* xc1 = xc0 + 64;
            #pragma unroll 2
            for (int i = 0; i < 8; ++i) {
                float fw[12];
                if (hasL) {
                    f4 v = *(const f4*)(xr + w0g - 4);
                    fw[0]=v.x; fw[1]=v.y; fw[2]=v.z; fw[3]=v.w;
                } else { fw[0]=0.f; fw[1]=0.f; fw[2]=0.f; fw[3]=0.f; }
                {
                    f4 v = *(const f4*)(xr + w0g);
                    fw[4]=v.x; fw[5]=v.y; fw[6]=v.z; fw[7]=v.w;
                }
                if (hasR) {
                    f4 v = *(const f4*)(xr + w0g + 4);
                    fw[8]=v.x; fw[9]=v.y; fw[10]=v.z; fw[11]=v.w;
                } else { fw[8]=0.f; fw[9]=0.f; fw[10]=0.f; fw[11]=0.f; }
                h2 f2[12];
                #pragma unroll
                for (int jj = 0; jj < 12; ++jj) f2[jj] = __builtin_bit_cast(h2, fw[jj]);
                if (use0) {
                    f4 c0 = *(const f4*)(xc0 + w0g);
                    h2 c02[4];
                    #pragma unroll
                    for (int p = 0; p < 4; ++p) c02[p] = __builtin_bit_cast(h2, c0[p]);
                    #pragma unroll
                    for (int dx = 0; dx < 7; ++dx)
                        #pragma unroll
                        for (int p = 0; p < 4; ++p)
                            sim0[dx][p] = fdot2f(c02[p], f2[dx + p + 1], sim0[dx][p]);
                }
                if (use1) {
                    f4 c1 = *(const f4*)(xc1 + w0g);
                    h2 c12[4];
                    #pragma unroll
                    for (int p = 0; p < 4; ++p) c12[p] = __builtin_bit_cast(h2, c1[p]);
                    #pragma unroll
                    for (int dx = 0; dx < 7; ++dx)
                        #pragma unroll
                        for (int p = 0; p < 4; ++p)
                            sim1[dx][p] = fdot2f(c12[p], f2[dx + p + 1], sim1[dx][p]);
                }
                xr  += 16 * HW;
                xc0 += 16 * HW;
                xc1 += 16 * HW;
            }
        }
        // reduce over cp (lane bits 3..5); wave-uniform guards
        if (use0) {
            #pragma unroll
            for (int dx = 0; dx < 7; ++dx)
                #pragma unroll
                for (int p = 0; p < 4; ++p) {
                    float v = sim0[dx][p];
                    v += __shfl_xor(v, 8);
                    v += __shfl_xor(v, 16);
                    v += __shfl_xor(v, 32);
                    sim0[dx][p] = v;
                }
        }
        if (use1) {
            #pragma unroll
            for (int dx = 0; dx < 7; ++dx)
                #pragma unroll
                for (int p = 0; p < 4; ++p) {
                    float v = sim1[dx][p];
                    v += __shfl_xor(v, 8);
                    v += __shfl_xor(v, 16);
                    v += __shfl_xor(v, 32);
                    sim1[dx][p] = v;
                }
        }
        if (cp == 0) {
            if (use0) {
                #pragma unroll
                for (int dx = 0; dx < 7; ++dx)
                    *(f4*)&simPart[0][g][r * 7 + dx][lw0] = *(const f4*)sim0[dx];
            }
            if (use1) {
                #pragma unroll
                for (int dx = 0; dx < 7; ++dx)
                    *(f4*)&simPart[1][g][(r - 1) * 7 + dx][lw0] = *(const f4*)sim1[dx];
            }
        }
    }
    __syncthreads();

    // ================= Softmax (both rows in parallel; hsel = t>>9) =================
    {
        const int hsel = t >> 9;
        const int tt = t & 511;
        const int w  = tt & 31;
        const int kc = tt >> 5;   // 0..15; kc<7 active
        float sred[7], e[7];
        if (kc < 7) {
            float lmax = -3.0e38f;
            #pragma unroll
            for (int jj = 0; jj < 7; ++jj) {
                const int idx = kc * 7 + jj;
                float s = simPart[hsel][0][idx][w] + simPart[hsel][1][idx][w];
                sred[jj] = s;
                lmax = fmaxf(lmax, s);
            }
            redBuf[hsel][kc][w] = lmax;
        }
        __syncthreads();
        if (kc < 7) {
            float m = redBuf[hsel][0][w];
            #pragma unroll
            for (int q = 1; q < 7; ++q) m = fmaxf(m, redBuf[hsel][q][w]);
            float ps = 0.f;
            #pragma unroll
            for (int jj = 0; jj < 7; ++jj) {
                e[jj] = __expf(sred[jj] - m);
                ps += e[jj];
            }
            psumBuf[hsel][kc][w] = ps;
        }
        __syncthreads();
        if (kc < 7) {
            float l = psumBuf[hsel][0][w];
            #pragma unroll
            for (int q = 1; q < 7; ++q) l += psumBuf[hsel][q][w];
            float rinv = 1.0f / l;
            #pragma unroll
            for (int jj = 0; jj < 7; ++jj) {
                _Float16 ah = (_Float16)(e[jj] * rinv);
                h2 av; av[0] = ah; av[1] = ah;
                attnH[hsel][kc * 7 + jj][w] = av;
            }
        }
    }
    __syncthreads();

    // ================= Phase B: 1 pair/thread, 8 shared row-windows =================
    // thread = (w4: bits 0..2, ci: t>>3 in 0..127). Row rr serves h0 (dy=rr)
    // and h1 (dy=rr-1).
    {
        const int w4 = t & 7;
        const int ci = t >> 3;           // pair -> channels 2ci, 2ci+1
        const int lw0 = w4 * 4;
        const int w0g = wbase + lw0;
        const bool hasL = (w0g != 0);
        const bool hasR = (w0g != 60);

        h2 acc0[4], acc1[4];
        #pragma unroll
        for (int p = 0; p < 4; ++p) {
            acc0[p][0] = (_Float16)0; acc0[p][1] = (_Float16)0;
            acc1[p][0] = (_Float16)0; acc1[p][1] = (_Float16)0;
        }

        const float* xbase = pw + (size_t)ci * HW;
        #pragma unroll 2
        for (int rr = 0; rr < 8; ++rr) {
            const int grow = h0 - 3 + rr;
            if (grow < 0 || grow >= Hdim) continue;   // block-uniform
            const float* xr = xbase + grow * 64;
            float fw[12];
            if (hasL) {
                f4 v = *(const f4*)(xr + w0g - 4);
                fw[0]=v.x; fw[1]=v.y; fw[2]=v.z; fw[3]=v.w;
            } else { fw[0]=0.f; fw[1]=0.f; fw[2]=0.f; fw[3]=0.f; }
            {
                f4 v = *(const f4*)(xr + w0g);
                fw[4]=v.x; fw[5]=v.y; fw[6]=v.z; fw[7]=v.w;
            }
            if (hasR) {
                f4 v = *(const f4*)(xr + w0g + 4);
                fw[8]=v.x; fw[9]=v.y; fw[10]=v.z; fw[11]=v.w;
            } else { fw[8]=0.f; fw[9]=0.f; fw[10]=0.f; fw[11]=0.f; }
            h2 f2[12];
            #pragma unroll
            for (int jj = 0; jj < 12; ++jj) f2[jj] = __builtin_bit_cast(h2, fw[jj]);
            if (rr <= 6) {
                #pragma unroll
                for (int dx = 0; dx < 7; ++dx) {
                    f4 av = *(const f4*)&attnH[0][rr * 7 + dx][lw0];
                    #pragma unroll
                    for (int p = 0; p < 4; ++p)
                        acc0[p] += __builtin_bit_cast(h2, av[p]) * f2[dx + p + 1];
                }
            }
            if (rr >= 1) {
                #pragma unroll
                for (int dx = 0; dx < 7; ++dx) {
                    f4 av = *(const f4*)&attnH[1][(rr - 1) * 7 + dx][lw0];
                    #pragma unroll
                    for (int p = 0; p < 4; ++p)
                        acc1[p] += __builtin_bit_cast(h2, av[p]) * f2[dx + p + 1];
                }
            }
        }

        float* ob = out + (size_t)b * (Cdim * HW) + w0g;
        f4 o00, o01, o10, o11;
        #pragma unroll
        for (int p = 0; p < 4; ++p) {
            o00[p] = (float)acc0[p][0];
            o01[p] = (float)acc0[p][1];
            o10[p] = (float)acc1[p][0];
            o11[p] = (float)acc1[p][1];
        }
        *(f4*)(ob + (size_t)(2 * ci) * HW     + h0 * 64) = o00;
        *(f4*)(ob + (size_t)(2 * ci + 1) * HW + h0 * 64) = o01;
        *(f4*)(ob + (size_t)(2 * ci) * HW     + h1 * 64) = o10;
        *(f4*)(ob + (size_t)(2 * ci + 1) * HW + h1 * 64) = o11;
    }
}

// ---------------------------------------------------------------------------
// Fallback: r11 fp32 champion (40.0us) if ws is too small for the packed copy.
// ---------------------------------------------------------------------------
__global__ __launch_bounds__(512, 2) void selfattn_fb(const float* __restrict__ x,
                                                      float* __restrict__ out)
{
    const int bid = blockIdx.x;
    const int k   = bid & 7;
    const int seq = bid >> 3;
    const int b   = k >> 1;
    const int h   = (k & 1) * 32 + (seq >> 1);
    const int wbase = (seq & 1) * 32;
    const int t = threadIdx.x;

    __shared__ float simRed[49][32];
    __shared__ float attnBuf[49][32];
    __shared__ float redBuf[7][32];
    __shared__ float psumBuf[7][32];

    const float* xb = x + (size_t)b * (Cdim * HW);

    {
        const int w4 = t & 7;
        const int cp = (t >> 3) & 7;
        const int dy = t >> 6;
        const int lw0 = w4 * 4;
        const int w0g = wbase + lw0;

        if (dy < 7) {
            float sim[7][4];
            #pragma unroll
            for (int dx = 0; dx < 7; ++dx)
                #pragma unroll
                for (int p = 0; p < 4; ++p) sim[dx][p] = 0.f;

            const int row = h + dy - 3;
            if (row >= 0 && row < Hdim) {
                const bool hasL = (w0g != 0);
                const bool hasR = (w0g != 60);
                const float* xrA = xb + (size_t)cp * HW + row * Wdim;
                const float* xcA = xb + (size_t)cp * HW + h   * Wdim;
                const float* xrB = xrA + (size_t)128 * HW;
                const float* xcB = xcA + (size_t)128 * HW;
                #pragma unroll 2
                for (int i = 0; i < 16; ++i) {
                    float fA[12], fB[12];
                    if (hasL) {
                        f4 v = *(const f4*)(xrA + w0g - 4);
                        fA[0]=v.x; fA[1]=v.y; fA[2]=v.z; fA[3]=v.w;
                    } else { fA[0]=0.f; fA[1]=0.f; fA[2]=0.f; fA[3]=0.f; }
                    {
                        f4 v = *(const f4*)(xrA + w0g);
                        fA[4]=v.x; fA[5]=v.y; fA[6]=v.z; fA[7]=v.w;
                    }
                    if (hasR) {
                        f4 v = *(const f4*)(xrA + w0g + 4);
                        fA[8]=v.x; fA[9]=v.y; fA[10]=v.z; fA[11]=v.w;
                    } else { fA[8]=0.f; fA[9]=0.f; fA[10]=0.f; fA[11]=0.f; }
                    if (hasL) {
                        f4 v = *(const f4*)(xrB + w0g - 4);
                        fB[0]=v.x; fB[1]=v.y; fB[2]=v.z; fB[3]=v.w;
                    } else { fB[0]=0.f; fB[1]=0.f; fB[2]=0.f; fB[3]=0.f; }
                    {
                        f4 v = *(const f4*)(xrB + w0g);
                        fB[4]=v.x; fB[5]=v.y; fB[6]=v.z; fB[7]=v.w;
                    }
                    if (hasR) {
                        f4 v = *(const f4*)(xrB + w0g + 4);
                        fB[8]=v.x; fB[9]=v.y; fB[10]=v.z; fB[11]=v.w;
                    } else { fB[8]=0.f; fB[9]=0.f; fB[10]=0.f; fB[11]=0.f; }
                    f4 cenA = *(const f4*)(xcA + w0g);
                    f4 cenB = *(const f4*)(xcB + w0g);
                    #pragma unroll
                    for (int dx = 0; dx < 7; ++dx)
                        #pragma unroll
                        for (int p = 0; p < 4; ++p)
                            sim[dx][p] += cenA[p] * fA[dx + p + 1]
                                        + cenB[p] * fB[dx + p + 1];
                    xrA += 8 * HW;  xcA += 8 * HW;
                    xrB += 8 * HW;  xcB += 8 * HW;
                }
            }
            #pragma unroll
            for (int dx = 0; dx < 7; ++dx)
                #pragma unroll
                for (int p = 0; p < 4; ++p) {
                    float v = sim[dx][p];
                    v += __shfl_xor(v, 8);
                    v += __shfl_xor(v, 16);
                    v += __shfl_xor(v, 32);
                    sim[dx][p] = v;
                }
            if (cp == 0) {
                #pragma unroll
                for (int dx = 0; dx < 7; ++dx)
                    *(f4*)&simRed[dy * 7 + dx][lw0] = *(const f4*)sim[dx];
            }
        }
    }
    __syncthreads();

    {
        const int w  = t & 31;
        const int kc = t >> 5;
        float sred[7], e[7];
        if (kc < 7) {
            float lmax = -3.0e38f;
            #pragma unroll
            for (int jj = 0; jj < 7; ++jj) {
                float s = simRed[kc * 7 + jj][w];
                sred[jj] = s;
                lmax = fmaxf(lmax, s);
            }
            redBuf[kc][w] = lmax;
        }
        __syncthreads();
        if (kc < 7) {
            float m = redBuf[0][w];
            #pragma unroll
            for (int q = 1; q < 7; ++q) m = fmaxf(m, redBuf[q][w]);
            float ps = 0.f;
            #pragma unroll
            for (int jj = 0; jj < 7; ++jj) {
                e[jj] = __expf(sred[jj] - m);
                ps += e[jj];
            }
            psumBuf[kc][w] = ps;
        }
        __syncthreads();
        if (kc < 7) {
            float l = psumBuf[0][w];
            #pragma unroll
            for (int q = 1; q < 7; ++q) l += psumBuf[q][w];
            float rinv = 1.0f / l;
            #pragma unroll
            for (int jj = 0; jj < 7; ++jj)
                attnBuf[kc * 7 + jj][w] = e[jj] * rinv;
        }
    }
    __syncthreads();

    {
        const int w4 = t & 7;
        const int ci = t >> 3;
        const int lw0 = w4 * 4;
        const int w0g = wbase + lw0;
        const int c0 = ci * 4;
        const bool hasL = (w0g != 0);
        const bool hasR = (w0g != 60);

        float acc[4][4];
        #pragma unroll
        for (int ch = 0; ch < 4; ++ch)
            #pragma unroll
            for (int p = 0; p < 4; ++p) acc[ch][p] = 0.f;

        for (int dy = 0; dy < 7; ++dy) {
            const int row = h + dy - 3;
            if (row < 0 || row >= Hdim) continue;
            float a[7][4];
            #pragma unroll
            for (int dx = 0; dx < 7; ++dx) {
                f4 v = *(const f4*)&attnBuf[dy * 7 + dx][lw0];
                a[dx][0]=v.x; a[dx][1]=v.y; a[dx][2]=v.z; a[dx][3]=v.w;
            }
            const float* xr = xb + (size_t)c0 * HW + row * Wdim;
            #pragma unroll
            for (int ch = 0; ch < 4; ++ch) {
                float fw[12];
                if (hasL) {
                    f4 v = *(const f4*)(xr + w0g - 4);
                    fw[0]=v.x; fw[1]=v.y; fw[2]=v.z; fw[3]=v.w;
                } else { fw[0]=0.f; fw[1]=0.f; fw[2]=0.f; fw[3]=0.f; }
                {
                    f4 v = *(const f4*)(xr + w0g);
                    fw[4]=v.x; fw[5]=v.y; fw[6]=v.z; fw[7]=v.w;
                }
                if (hasR) {
                    f4 v = *(const f4*)(xr + w0g + 4);
                    fw[8]=v.x; fw[9]=v.y; fw[10]=v.z; fw[11]=v.w;
                } else { fw[8]=0.f; fw[9]=0.f; fw[10]=0.f; fw[11]=0.f; }
                #pragma unroll
                for (int dx = 0; dx < 7; ++dx)
                    #pragma unroll
                    for (int p = 0; p < 4; ++p)
                        acc[ch][p] += a[dx][p] * fw[dx + p + 1];
                xr += HW;
            }
        }

        float* ob = out + (size_t)b * (Cdim * HW) + h * Wdim + wbase;
        #pragma unroll
        for (int ch = 0; ch < 4; ++ch)
            *(f4*)(ob + (size_t)(c0 + ch) * HW + lw0) = *(const f4*)acc[ch];
    }
}

extern "C" void kernel_launch(void* const* d_in, const int* in_sizes, int n_in,
                              void* d_out, int out_size, void* d_ws, size_t ws_size,
                              hipStream_t stream)
{
    const float* x = (const float*)d_in[0];
    float* out = (float*)d_out;
    const size_t need = (size_t)4 * 128 * HW * 4;   // 8 MB packed half2
    if (ws_size >= need) {
        float* pw = (float*)d_ws;
        pack_kernel<<<dim3(1024), 512, 0, stream>>>(x, pw);
        selfattn_hpair<<<dim3(256), 1024, 0, stream>>>(pw, out);
    } else {
        selfattn_fb<<<dim3(512), 512, 0, stream>>>(x, out);
    }
}